// Round 1
// baseline (240.852 us; speedup 1.0000x reference)
//
#include <hip/hip_runtime.h>
#include <math.h>

// Problem constants (fixed by setup_inputs): B=2, C=64, H=W=56, R=9
#define BB   2
#define BCH  64
#define NPOS 3136   // 56*56
#define RR   9
#define NEGINF (-1e9f)

// ---------------------------------------------------------------------------
// Kernel 1: per-position normalization (center + L2 over channels) into
// position-major [B][N][C] layout, plus V packing and mask bitfields.
// Thread = one (b, n). Channel loop reads are coalesced across lanes.
// ---------------------------------------------------------------------------
__global__ __launch_bounds__(256) void prep_kernel(
    const float* __restrict__ fA, const float* __restrict__ fT,
    const float* __restrict__ It, const int* __restrict__ mA,
    const int* __restrict__ mT,
    float* __restrict__ fAn, float* __restrict__ fTn,
    float4* __restrict__ Vt, unsigned* __restrict__ mTb,
    unsigned* __restrict__ rsel) {
  int idx = blockIdx.x * blockDim.x + threadIdx.x;
  if (idx >= BB * NPOS) return;
  int b = idx / NPOS, n = idx - b * NPOS;

  // --- normalize fA column n ---
  {
    const float* src = fA + (size_t)b * BCH * NPOS + n;
    float x[BCH];
    float mean = 0.f;
#pragma unroll
    for (int c = 0; c < BCH; ++c) { x[c] = src[(size_t)c * NPOS]; mean += x[c]; }
    mean *= (1.0f / BCH);
    float ss = 0.f;
#pragma unroll
    for (int c = 0; c < BCH; ++c) { x[c] -= mean; ss += x[c] * x[c]; }
    float inv = 1.0f / (sqrtf(ss) + 1e-8f);
    float* dst = fAn + (size_t)idx * BCH;
#pragma unroll
    for (int c = 0; c < BCH; ++c) dst[c] = x[c] * inv;
  }
  // --- normalize fT column n ---
  {
    const float* src = fT + (size_t)b * BCH * NPOS + n;
    float x[BCH];
    float mean = 0.f;
#pragma unroll
    for (int c = 0; c < BCH; ++c) { x[c] = src[(size_t)c * NPOS]; mean += x[c]; }
    mean *= (1.0f / BCH);
    float ss = 0.f;
#pragma unroll
    for (int c = 0; c < BCH; ++c) { x[c] -= mean; ss += x[c] * x[c]; }
    float inv = 1.0f / (sqrtf(ss) + 1e-8f);
    float* dst = fTn + (size_t)idx * BCH;
#pragma unroll
    for (int c = 0; c < BCH; ++c) dst[c] = x[c] * inv;
  }
  // --- V = I_t[b, 0:3, n], packed as float4 ---
  Vt[idx] = make_float4(It[((size_t)b * 3 + 0) * NPOS + n],
                        It[((size_t)b * 3 + 1) * NPOS + n],
                        It[((size_t)b * 3 + 2) * NPOS + n], 0.f);
  // --- target-mask bitfield (bit r = masks_t[b,r,n] > 0) ---
  unsigned mt = 0;
#pragma unroll
  for (int r = 0; r < RR; ++r)
    mt |= (mT[((size_t)b * RR + r) * NPOS + n] > 0 ? 1u : 0u) << r;
  mTb[idx] = mt;
  // --- anchor-region select: last r in [0,8) with masks_a>0 (15 = none),
  //     plus inpaint flag (masks_a[b,8,n] > 0) in bit 4 ---
  unsigned rh = 15u;
#pragma unroll
  for (int r = 0; r < RR - 1; ++r)
    if (mA[((size_t)b * RR + r) * NPOS + n] > 0) rh = (unsigned)r;
  unsigned gi = mA[((size_t)b * RR + 8) * NPOS + n] > 0 ? 1u : 0u;
  rsel[idx] = rh | (gi << 4);
}

// ---------------------------------------------------------------------------
// Kernel 2: flash-style attend, thread-per-anchor-position p, dual online
// softmax (gen_h region rh(p) and inpaint region 8), split over q-chunks.
// K row / V / mask addresses are wave-uniform -> scalar loads + broadcast.
// Writes split-K partials (m, l, acc[3]) per (b, chunk, region, p).
// ---------------------------------------------------------------------------
__global__ __launch_bounds__(256) void attend_kernel(
    const float* __restrict__ fAn, const float* __restrict__ fTn,
    const float4* __restrict__ Vt, const unsigned* __restrict__ mTb,
    const unsigned* __restrict__ rsel,
    float4* __restrict__ partA, float4* __restrict__ partB, int NQ) {
  int p = blockIdx.x * blockDim.x + threadIdx.x;
  int b = blockIdx.z;
  int cy = blockIdx.y;
  if (p >= NPOS) return;

  int chunk = (NPOS + NQ - 1) / NQ;
  int q0 = cy * chunk;
  int q1 = min(NPOS, q0 + chunk);

  // Q row (64 floats) into registers, statically indexed.
  const float4* Q4 = (const float4*)(fAn + ((size_t)b * NPOS + p) * BCH);
  float4 qv[16];
#pragma unroll
  for (int k = 0; k < 16; ++k) qv[k] = Q4[k];

  unsigned rs = rsel[b * NPOS + p];
  unsigned rh = rs & 0xFu;  // 15 => no gen_h region; bit never set in mTb => always masked out

  float mH = NEGINF, lH = 0.f, aH0 = 0.f, aH1 = 0.f, aH2 = 0.f;
  float mI = NEGINF, lI = 0.f, aI0 = 0.f, aI1 = 0.f, aI2 = 0.f;

  const float4* K4base = (const float4*)(fTn + (size_t)b * NPOS * BCH);
  const float4* Vb = Vt + b * NPOS;
  const unsigned* Mb = mTb + b * NPOS;

  for (int q = q0; q < q1; ++q) {
    const float4* K4 = K4base + (size_t)q * 16;
    float sx = 0.f, sy = 0.f, sz = 0.f, sw = 0.f;
#pragma unroll
    for (int k = 0; k < 16; ++k) {
      float4 kk = K4[k];  // uniform address across wave
      sx += qv[k].x * kk.x;
      sy += qv[k].y * kk.y;
      sz += qv[k].z * kk.z;
      sw += qv[k].w * kk.w;
    }
    float s = ((sx + sy) + (sz + sw)) * 100.0f;  // / temperature(0.01)

    unsigned mt = Mb[q];
    float4 vv = Vb[q];

    // region rh (gen_h), branchless online softmax
    {
      float lg = ((mt >> rh) & 1u) ? s : NEGINF;
      float mn = fmaxf(mH, lg);
      float sc = __expf(mH - mn);
      float pw = __expf(lg - mn);
      lH = lH * sc + pw;
      aH0 = aH0 * sc + pw * vv.x;
      aH1 = aH1 * sc + pw * vv.y;
      aH2 = aH2 * sc + pw * vv.z;
      mH = mn;
    }
    // region 8 (gen_i)
    {
      float lg = ((mt >> 8) & 1u) ? s : NEGINF;
      float mn = fmaxf(mI, lg);
      float sc = __expf(mI - mn);
      float pw = __expf(lg - mn);
      lI = lI * sc + pw;
      aI0 = aI0 * sc + pw * vv.x;
      aI1 = aI1 * sc + pw * vv.y;
      aI2 = aI2 * sc + pw * vv.z;
      mI = mn;
    }
  }

  size_t rec = ((size_t)(b * gridDim.y + cy) * 2 + 0) * NPOS + p;
  partA[rec] = make_float4(mH, lH, aH0, aH1);
  partB[rec] = make_float4(aH2, 0.f, 0.f, 0.f);
  rec = ((size_t)(b * gridDim.y + cy) * 2 + 1) * NPOS + p;
  partA[rec] = make_float4(mI, lI, aI0, aI1);
  partB[rec] = make_float4(aI2, 0.f, 0.f, 0.f);
}

// ---------------------------------------------------------------------------
// Kernel 3: split-K combine + final normalize + validity zeroing + output.
// out = [gen_h (B,3,N), gen_i (B,3,N)] flat.
// ---------------------------------------------------------------------------
__global__ __launch_bounds__(256) void combine_kernel(
    const float4* __restrict__ partA, const float4* __restrict__ partB,
    const unsigned* __restrict__ rsel, float* __restrict__ out, int NQ) {
  int idx = blockIdx.x * blockDim.x + threadIdx.x;
  if (idx >= BB * NPOS) return;
  int b = idx / NPOS, p = idx - b * NPOS;
  unsigned rs = rsel[idx];

#pragma unroll
  for (int reg = 0; reg < 2; ++reg) {
    float M = NEGINF;
    for (int cy = 0; cy < NQ; ++cy) {
      size_t rec = ((size_t)(b * NQ + cy) * 2 + reg) * NPOS + p;
      M = fmaxf(M, partA[rec].x);
    }
    float L = 0.f, A0 = 0.f, A1 = 0.f, A2 = 0.f;
    for (int cy = 0; cy < NQ; ++cy) {
      size_t rec = ((size_t)(b * NQ + cy) * 2 + reg) * NPOS + p;
      float4 a = partA[rec];
      float4 bb = partB[rec];
      float w = __expf(a.x - M);
      L += a.y * w;
      A0 += a.z * w;
      A1 += a.w * w;
      A2 += bb.x * w;
    }
    float invL = 1.0f / L;  // L > 0 always (all-masked case gives L = N)
    float o0 = A0 * invL, o1 = A1 * invL, o2 = A2 * invL;
    bool valid = (reg == 0) ? ((rs & 0xFu) != 15u) : (((rs >> 4) & 1u) != 0u);
    if (!valid) { o0 = 0.f; o1 = 0.f; o2 = 0.f; }
    size_t base = (reg ? (size_t)BB * 3 * NPOS : 0) + (size_t)b * 3 * NPOS + p;
    out[base] = o0;
    out[base + NPOS] = o1;
    out[base + 2 * NPOS] = o2;
  }
}

// ---------------------------------------------------------------------------
extern "C" void kernel_launch(void* const* d_in, const int* in_sizes, int n_in,
                              void* d_out, int out_size, void* d_ws, size_t ws_size,
                              hipStream_t stream) {
  const float* fA = (const float*)d_in[0];
  const float* fT = (const float*)d_in[1];
  const float* It = (const float*)d_in[2];
  const int* mA = (const int*)d_in[3];
  const int* mT = (const int*)d_in[4];
  float* out = (float*)d_out;

  // Workspace layout (float offsets; all multiples of 4 -> 16B aligned)
  const size_t NF = (size_t)BB * NPOS * BCH;  // 401408
  const size_t off_fAn = 0;
  const size_t off_fTn = off_fAn + NF;
  const size_t off_Vt = off_fTn + NF;                    // BB*NPOS float4s
  const size_t off_mTb = off_Vt + (size_t)BB * NPOS * 4; // BB*NPOS uints
  const size_t off_rsel = off_mTb + (size_t)BB * NPOS;
  const size_t off_part = off_rsel + (size_t)BB * NPOS;

  // Choose NQ (q-split factor) to fit partials in ws: partA+partB floats =
  // BB*NQ*2 records * NPOS * 8 floats.
  int NQ = 32;
  while (NQ > 1) {
    size_t need = (off_part + (size_t)BB * NQ * 2 * NPOS * 8) * sizeof(float);
    if (need <= ws_size) break;
    NQ >>= 1;
  }
  float* w = (float*)d_ws;
  float* fAn = w + off_fAn;
  float* fTn = w + off_fTn;
  float4* Vt = (float4*)(w + off_Vt);
  unsigned* mTb = (unsigned*)(w + off_mTb);
  unsigned* rsel = (unsigned*)(w + off_rsel);
  float4* partA = (float4*)(w + off_part);
  float4* partB = partA + (size_t)BB * NQ * 2 * NPOS;

  int nthreads = BB * NPOS;
  int nblk = (nthreads + 255) / 256;

  prep_kernel<<<nblk, 256, 0, stream>>>(fA, fT, It, mA, mT, fAn, fTn, Vt, mTb, rsel);

  dim3 g2((NPOS + 255) / 256, NQ, BB);
  attend_kernel<<<g2, 256, 0, stream>>>(fAn, fTn, Vt, mTb, rsel, partA, partB, NQ);

  combine_kernel<<<nblk, 256, 0, stream>>>(partA, partB, rsel, out, NQ);
}

// Round 4
// 171.686 us; speedup vs baseline: 1.4029x; 1.4029x over previous
//
#include <hip/hip_runtime.h>
#include <math.h>

// Problem constants (fixed by setup_inputs): B=2, C=64, H=W=56, R=9
// NOTE (round 4 resubmit): rounds 2-3 benches never ran (GPU acquisition
// timeout); same source resubmitted for a clean first measurement.
#define BB   2
#define BCH  64
#define NPOS 3136   // 56*56
#define RR   9

// ---------------------------------------------------------------------------
// Kernel 1: wave-per-(b,n). Lane = channel. Center + L2-normalize fA and fT
// columns into position-major [B*N][64] (coalesced 256B stores). Also packs
// V = I_t (w component = 1.0 so the softmax denominator rides the 4th fma
// lane), the 9-bit target-mask bitfield, and the anchor region selector.
// 6272 wave-tasks -> 1568 blocks: full-device parallelism.
// ---------------------------------------------------------------------------
__global__ __launch_bounds__(256) void prep_kernel(
    const float* __restrict__ fA, const float* __restrict__ fT,
    const float* __restrict__ It, const int* __restrict__ mA,
    const int* __restrict__ mT,
    float* __restrict__ fAn, float* __restrict__ fTn,
    float* __restrict__ Vt, unsigned* __restrict__ mTb,
    unsigned* __restrict__ rsel) {
  int gtid = blockIdx.x * blockDim.x + threadIdx.x;
  int wid = gtid >> 6;            // one wave per (b, n)
  int lane = threadIdx.x & 63;
  if (wid >= BB * NPOS) return;
  int b = wid / NPOS, n = wid - b * NPOS;

  const float* srcs[2] = {fA, fT};
  float* dsts[2] = {fAn, fTn};
#pragma unroll
  for (int t = 0; t < 2; ++t) {
    // lane c loads x = src[b, c, n]  (per-lane gather, stride NPOS*4B)
    float v = srcs[t][((size_t)b * BCH + lane) * NPOS + n];
    float s1 = v, s2 = v * v;
#pragma unroll
    for (int off = 32; off; off >>= 1) {
      s1 += __shfl_xor(s1, off);
      s2 += __shfl_xor(s2, off);
    }
    float mean = s1 * (1.0f / BCH);
    float var = fmaxf(s2 - s1 * mean, 0.0f);   // sum((x-m)^2) = s2 - s1*mean
    float inv = 1.0f / (sqrtf(var) + 1e-8f);
    dsts[t][(size_t)wid * BCH + lane] = (v - mean) * inv;  // coalesced
  }

  // V pack: [v0, v1, v2, 1.0]  (w=1 -> denominator accumulates via same fma)
  if (lane < 3) Vt[(size_t)wid * 4 + lane] = It[((size_t)b * 3 + lane) * NPOS + n];
  if (lane == 3) Vt[(size_t)wid * 4 + 3] = 1.0f;

  // target-mask bitfield + anchor region select, via 16-lane reduction
  unsigned mtbit = 0;
  int rhv = -1;
  unsigned giv = 0;
  if (lane < RR)
    mtbit = (mT[((size_t)b * RR + lane) * NPOS + n] > 0) ? (1u << lane) : 0u;
  if (lane < RR - 1)
    rhv = (mA[((size_t)b * RR + lane) * NPOS + n] > 0) ? lane : -1;
  if (lane == 8)
    giv = (mA[((size_t)b * RR + 8) * NPOS + n] > 0) ? 16u : 0u;
#pragma unroll
  for (int off = 8; off; off >>= 1) {
    mtbit |= (unsigned)__shfl_xor((int)mtbit, off);
    rhv = max(rhv, __shfl_xor(rhv, off));
    giv |= (unsigned)__shfl_xor((int)giv, off);
  }
  if (lane == 0) {
    mTb[wid] = mtbit;
    rsel[wid] = (unsigned)(rhv < 0 ? 15 : rhv) | giv;
  }
}

// ---------------------------------------------------------------------------
// Kernel 2: flash-style attend, thread per anchor position p, split over NQ
// q-chunks. FIXED softmax max = 100 (logits = corr*100 <= 100 exactly), so:
//   - single exp per q, shared by both regions (gated by cndmask)
//   - no online-max chain, no rescale
//   - split-K partial is just {a0,a1,a2,l} -- combine is a plain sum.
// K row / V / mask addresses are wave-uniform -> scalar loads + broadcast.
// ---------------------------------------------------------------------------
__global__ __launch_bounds__(256) void attend_kernel(
    const float* __restrict__ fAn, const float* __restrict__ fTn,
    const float4* __restrict__ Vt, const unsigned* __restrict__ mTb,
    const unsigned* __restrict__ rsel,
    float4* __restrict__ part, int NQ, int chunk) {
  int p = blockIdx.x * blockDim.x + threadIdx.x;
  int b = blockIdx.z;
  int cy = blockIdx.y;
  if (p >= NPOS) return;

  int q0 = cy * chunk;
  int q1 = min(NPOS, q0 + chunk);

  // Q row (64 floats) into registers, statically indexed.
  const float4* Q4 = (const float4*)(fAn + ((size_t)b * NPOS + p) * BCH);
  float4 qv[16];
#pragma unroll
  for (int k = 0; k < 16; ++k) qv[k] = Q4[k];

  unsigned rs = rsel[b * NPOS + p];
  unsigned bitH = 1u << (rs & 0xFu);  // rs==15 -> bit 15, never set in mTb

  float4 aH = make_float4(0.f, 0.f, 0.f, 0.f);  // {a0,a1,a2,l}
  float4 aI = make_float4(0.f, 0.f, 0.f, 0.f);

  const float4* K4base = (const float4*)(fTn + (size_t)b * NPOS * BCH);
  const float4* Vb = Vt + b * NPOS;
  const unsigned* Mb = mTb + b * NPOS;

  for (int q = q0; q < q1; ++q) {
    const float4* K4 = K4base + (size_t)q * 16;
    float sx = 0.f, sy = 0.f, sz = 0.f, sw = 0.f;
#pragma unroll
    for (int k = 0; k < 16; ++k) {
      float4 kk = K4[k];  // uniform address across wave -> scalar loads
      sx += qv[k].x * kk.x;
      sy += qv[k].y * kk.y;
      sz += qv[k].z * kk.z;
      sw += qv[k].w * kk.w;
    }
    float s = (sx + sy) + (sz + sw);           // corr in [-1, 1]
    float e = __expf(fmaf(s, 100.f, -100.f));  // exp(s/T - max), max = 100

    unsigned mt = Mb[q];
    float4 vv = Vb[q];  // {v0, v1, v2, 1.0}

    float pwH = (mt & bitH) ? e : 0.f;
    float pwI = (mt & 256u) ? e : 0.f;
    aH.x = fmaf(pwH, vv.x, aH.x);
    aH.y = fmaf(pwH, vv.y, aH.y);
    aH.z = fmaf(pwH, vv.z, aH.z);
    aH.w = fmaf(pwH, vv.w, aH.w);
    aI.x = fmaf(pwI, vv.x, aI.x);
    aI.y = fmaf(pwI, vv.y, aI.y);
    aI.z = fmaf(pwI, vv.z, aI.z);
    aI.w = fmaf(pwI, vv.w, aI.w);
  }

  part[(((size_t)(b * 2 + 0) * NPOS + p) * NQ + cy)] = aH;
  part[(((size_t)(b * 2 + 1) * NPOS + p) * NQ + cy)] = aI;
}

// ---------------------------------------------------------------------------
// Kernel 3: wave per (b, region, p): butterfly-sum the NQ partials (lane=cy,
// contiguous 16B/lane loads), normalize, apply anchor-validity zeroing.
// out = [gen_h (B,3,N), gen_i (B,3,N)] flat.
// ---------------------------------------------------------------------------
__global__ __launch_bounds__(256) void combine_kernel(
    const float4* __restrict__ part, const unsigned* __restrict__ rsel,
    float* __restrict__ out, int NQ) {
  int gtid = blockIdx.x * blockDim.x + threadIdx.x;
  int task = gtid >> 6;
  int lane = threadIdx.x & 63;
  if (task >= BB * 2 * NPOS) return;
  int breg = task / NPOS;
  int p = task - breg * NPOS;
  int b = breg >> 1, reg = breg & 1;

  float4 v = (lane < NQ) ? part[(size_t)task * NQ + lane]
                         : make_float4(0.f, 0.f, 0.f, 0.f);
#pragma unroll
  for (int off = 32; off; off >>= 1) {
    v.x += __shfl_xor(v.x, off);
    v.y += __shfl_xor(v.y, off);
    v.z += __shfl_xor(v.z, off);
    v.w += __shfl_xor(v.w, off);
  }
  if (lane == 0) {
    unsigned rs = rsel[b * NPOS + p];
    bool valid = reg ? ((rs >> 4) & 1u) : ((rs & 0xFu) != 15u);
    float invL = (valid && v.w > 0.f) ? 1.0f / v.w : 0.0f;
    size_t base = (size_t)reg * BB * 3 * NPOS + (size_t)b * 3 * NPOS + p;
    out[base] = v.x * invL;
    out[base + NPOS] = v.y * invL;
    out[base + 2 * NPOS] = v.z * invL;
  }
}

// ---------------------------------------------------------------------------
extern "C" void kernel_launch(void* const* d_in, const int* in_sizes, int n_in,
                              void* d_out, int out_size, void* d_ws, size_t ws_size,
                              hipStream_t stream) {
  const float* fA = (const float*)d_in[0];
  const float* fT = (const float*)d_in[1];
  const float* It = (const float*)d_in[2];
  const int* mA = (const int*)d_in[3];
  const int* mT = (const int*)d_in[4];
  float* out = (float*)d_out;

  // Workspace layout (float offsets; all multiples of 4 -> 16B aligned)
  const size_t NF = (size_t)BB * NPOS * BCH;  // 401408
  const size_t off_fAn = 0;
  const size_t off_fTn = off_fAn + NF;
  const size_t off_Vt = off_fTn + NF;                     // BB*NPOS float4s
  const size_t off_mTb = off_Vt + (size_t)BB * NPOS * 4;  // BB*NPOS uints
  const size_t off_rsel = off_mTb + (size_t)BB * NPOS;
  const size_t off_part = off_rsel + (size_t)BB * NPOS;

  // NQ = q-split factor (power of 2, <= 64 so combine fits one wave).
  int NQ = 64;
  while (NQ > 1) {
    size_t need = (off_part + (size_t)BB * 2 * NPOS * NQ * 4) * sizeof(float);
    if (need <= ws_size) break;
    NQ >>= 1;
  }
  float* w = (float*)d_ws;
  float* fAn = w + off_fAn;
  float* fTn = w + off_fTn;
  float* Vt = w + off_Vt;
  unsigned* mTb = (unsigned*)(w + off_mTb);
  unsigned* rsel = (unsigned*)(w + off_rsel);
  float4* part = (float4*)(w + off_part);

  int chunk = (NPOS + NQ - 1) / NQ;

  // prep: wave per (b,n) -> BB*NPOS waves, 4 per block
  int nwave1 = BB * NPOS;
  prep_kernel<<<(nwave1 * 64 + 255) / 256, 256, 0, stream>>>(
      fA, fT, It, mA, mT, fAn, fTn, Vt, mTb, rsel);

  dim3 g2((NPOS + 255) / 256, NQ, BB);
  attend_kernel<<<g2, 256, 0, stream>>>(fAn, fTn, (const float4*)Vt, mTb, rsel,
                                        part, NQ, chunk);

  // combine: wave per (b, region, p) -> BB*2*NPOS waves
  int nwave3 = BB * 2 * NPOS;
  combine_kernel<<<(nwave3 * 64 + 255) / 256, 256, 0, stream>>>(part, rsel, out, NQ);
}

// Round 6
// 127.300 us; speedup vs baseline: 1.8920x; 1.3487x over previous
//
#include <hip/hip_runtime.h>
#include <math.h>

// Problem constants (fixed by setup_inputs): B=2, C=64, H=W=56, R=9
// NOTE (round 6 resubmit): round-5 bench never ran (GPU acquisition timeout);
// identical source resubmitted for first measurement of the MFMA redesign.
#define BB   2
#define BCH  64
#define NPOS 3136   // 56*56, = 49*64, = 196*16
#define RR   9

typedef __attribute__((ext_vector_type(8))) short short8;  // 8 bf16 = 4 VGPR
typedef __attribute__((ext_vector_type(4))) float f32x4;

static __device__ __forceinline__ ushort f2bf(float x) {  // RNE float->bf16
  unsigned u = __float_as_uint(x);
  return (ushort)((u + 0x7fffu + ((u >> 16) & 1u)) >> 16);
}
static __device__ __forceinline__ float bf2f(ushort h) {
  return __uint_as_float(((unsigned)h) << 16);
}
static __device__ __forceinline__ f32x4 mfma_bf16(short8 a, short8 b, f32x4 c) {
  return __builtin_amdgcn_mfma_f32_16x16x32_bf16(a, b, c, 0, 0, 0);
}

// ---------------------------------------------------------------------------
// Kernel 1: wave per 4 consecutive positions (b, n0..n0+3). Lane = channel.
// float4 gather per lane (16B/line instead of 4B), butterfly mean/var for the
// 4 positions at once, emit split-bf16 hi/lo of the normalized value into
// position-major [B*N][64] bf16 arrays (128B coalesced stores per n).
// Lanes 0..35 handle masks (r = lane>>2, j = lane&3), lanes 0..3 pack V.
// 1568 waves -> 392 blocks.
// ---------------------------------------------------------------------------
__global__ __launch_bounds__(256) void prep2(
    const float* __restrict__ fA, const float* __restrict__ fT,
    const float* __restrict__ It, const int* __restrict__ mA,
    const int* __restrict__ mT,
    ushort* __restrict__ Qhi, ushort* __restrict__ Qlo,
    ushort* __restrict__ Khi, ushort* __restrict__ Klo,
    float4* __restrict__ Vt, unsigned* __restrict__ mTb,
    unsigned* __restrict__ rsel) {
  int wid = (blockIdx.x * blockDim.x + threadIdx.x) >> 6;
  int lane = threadIdx.x & 63;
  if (wid >= BB * (NPOS / 4)) return;
  int b = wid / (NPOS / 4);
  int n0 = (wid - b * (NPOS / 4)) * 4;

  const float* srcs[2] = {fA, fT};
  ushort* his[2] = {Qhi, Khi};
  ushort* los[2] = {Qlo, Klo};
#pragma unroll
  for (int t = 0; t < 2; ++t) {
    float4 x = *(const float4*)(srcs[t] + ((size_t)b * BCH + lane) * NPOS + n0);
    float4 s1 = x;
    float4 s2 = make_float4(x.x * x.x, x.y * x.y, x.z * x.z, x.w * x.w);
#pragma unroll
    for (int off = 32; off; off >>= 1) {
      s1.x += __shfl_xor(s1.x, off); s1.y += __shfl_xor(s1.y, off);
      s1.z += __shfl_xor(s1.z, off); s1.w += __shfl_xor(s1.w, off);
      s2.x += __shfl_xor(s2.x, off); s2.y += __shfl_xor(s2.y, off);
      s2.z += __shfl_xor(s2.z, off); s2.w += __shfl_xor(s2.w, off);
    }
    float xs[4] = {x.x, x.y, x.z, x.w};
    float s1a[4] = {s1.x, s1.y, s1.z, s1.w};
    float s2a[4] = {s2.x, s2.y, s2.z, s2.w};
#pragma unroll
    for (int j = 0; j < 4; ++j) {
      float mean = s1a[j] * (1.0f / BCH);
      float var = fmaxf(s2a[j] - s1a[j] * mean, 0.0f);
      float inv = 1.0f / (sqrtf(var) + 1e-8f);
      float v = (xs[j] - mean) * inv;
      ushort h = f2bf(v);
      ushort l = f2bf(v - bf2f(h));
      size_t o = ((size_t)b * NPOS + n0 + j) * BCH + lane;
      his[t][o] = h;
      los[t][o] = l;
    }
  }

  // masks: r = lane>>2 (region), j = lane&3 (which of the 4 positions)
  int r = lane >> 2, j = lane & 3;
  int n = n0 + j;
  unsigned mtbit = 0, giv = 0;
  int rhv = -1;
  if (r < RR) {
    mtbit = (mT[((size_t)b * RR + r) * NPOS + n] > 0) ? (1u << r) : 0u;
    int a = (mA[((size_t)b * RR + r) * NPOS + n] > 0);
    if (r < RR - 1) rhv = a ? r : -1;
    else giv = a ? 16u : 0u;
  }
#pragma unroll
  for (int off = 32; off >= 4; off >>= 1) {  // xor multiples of 4 keep j fixed
    mtbit |= (unsigned)__shfl_xor((int)mtbit, off);
    rhv = max(rhv, __shfl_xor(rhv, off));
    giv |= (unsigned)__shfl_xor((int)giv, off);
  }
  if (lane < 4) {
    mTb[(size_t)b * NPOS + n] = mtbit;
    rsel[(size_t)b * NPOS + n] = (unsigned)(rhv < 0 ? 15 : rhv) | giv;
    float4 v;
    v.x = It[((size_t)b * 3 + 0) * NPOS + n];
    v.y = It[((size_t)b * 3 + 1) * NPOS + n];
    v.z = It[((size_t)b * 3 + 2) * NPOS + n];
    v.w = 1.0f;  // denominator rides the 4th fma lane
    Vt[(size_t)b * NPOS + n] = v;
  }
}

// ---------------------------------------------------------------------------
// Kernel 2: MFMA attend. Block = 4 waves, each wave owns 16 p's; grid =
// (49 p-tiles, NQ q-chunks, B). Per 16-q tile: 6 chained mfma_16x16x32_bf16
// implement split-bf16 fp32 GEMM (Khi*Qhi + Khi*Qlo + Klo*Qhi).
// Orientation mfma(K,Q): D[row=q][col=p]; lane holds p=lane&15,
// q = (lane>>4)*4 + r (m89-verified). Epilogue: fixed-max exp (logit<=100
// since rows are unit-norm), dual region gating, in-register PV accumulate;
// 2-stage shfl_xor folds the 4 q-groups per p. No LDS, no online max.
// ---------------------------------------------------------------------------
__global__ __launch_bounds__(256) void attend_mfma(
    const ushort* __restrict__ Qhi, const ushort* __restrict__ Qlo,
    const ushort* __restrict__ Khi, const ushort* __restrict__ Klo,
    const float4* __restrict__ Vt, const unsigned* __restrict__ mTb,
    const unsigned* __restrict__ rsel, float4* __restrict__ part,
    int NQ, int ntiles) {
  const int lane = threadIdx.x & 63;
  const int wav = threadIdx.x >> 6;
  const int b = blockIdx.z, cy = blockIdx.y;
  const int p = blockIdx.x * 64 + wav * 16 + (lane & 15);
  const int kofs = (lane >> 4) * 8;

  const size_t qoff = ((size_t)b * NPOS + p) * BCH;
  short8 qh0 = *(const short8*)(Qhi + qoff + kofs);
  short8 qh1 = *(const short8*)(Qhi + qoff + 32 + kofs);
  short8 ql0 = *(const short8*)(Qlo + qoff + kofs);
  short8 ql1 = *(const short8*)(Qlo + qoff + 32 + kofs);

  const unsigned bitH = 1u << (rsel[(size_t)b * NPOS + p] & 0xFu);
  f32x4 aH = {0.f, 0.f, 0.f, 0.f}, aI = {0.f, 0.f, 0.f, 0.f};

  const unsigned* Mb = mTb + (size_t)b * NPOS;
  const float4* Vb = Vt + (size_t)b * NPOS;
  const ushort* KhiB = Khi + (size_t)b * NPOS * BCH;
  const ushort* KloB = Klo + (size_t)b * NPOS * BCH;

  int qb = cy * ntiles * 16;
  for (int t = 0; t < ntiles; ++t, qb += 16) {
    size_t aoff = (size_t)(qb + (lane & 15)) * BCH;
    short8 kh0 = *(const short8*)(KhiB + aoff + kofs);
    short8 kh1 = *(const short8*)(KhiB + aoff + 32 + kofs);
    short8 kl0 = *(const short8*)(KloB + aoff + kofs);
    short8 kl1 = *(const short8*)(KloB + aoff + 32 + kofs);
    f32x4 acc = {0.f, 0.f, 0.f, 0.f};
    acc = mfma_bf16(kh0, qh0, acc);
    acc = mfma_bf16(kh1, qh1, acc);
    acc = mfma_bf16(kh0, ql0, acc);
    acc = mfma_bf16(kh1, ql1, acc);
    acc = mfma_bf16(kl0, qh0, acc);
    acc = mfma_bf16(kl1, qh1, acc);

    int qe = qb + (lane >> 4) * 4;
    uint4 mt4 = *(const uint4*)(Mb + qe);
    unsigned mts[4] = {mt4.x, mt4.y, mt4.z, mt4.w};
#pragma unroll
    for (int rr = 0; rr < 4; ++rr) {
      // exp(100*s - 100) = exp2(144.2695*(s-1)); s<=1 exactly (unit vectors)
      float e = exp2f(fmaf(acc[rr], 144.26950408889634f, -144.26950408889634f));
      float4 vv = Vb[qe + rr];
      float pwH = (mts[rr] & bitH) ? e : 0.f;
      float pwI = (mts[rr] & 256u) ? e : 0.f;
      aH.x = fmaf(pwH, vv.x, aH.x); aH.y = fmaf(pwH, vv.y, aH.y);
      aH.z = fmaf(pwH, vv.z, aH.z); aH.w = fmaf(pwH, vv.w, aH.w);
      aI.x = fmaf(pwI, vv.x, aI.x); aI.y = fmaf(pwI, vv.y, aI.y);
      aI.z = fmaf(pwI, vv.z, aI.z); aI.w = fmaf(pwI, vv.w, aI.w);
    }
  }
  // fold the 4 q-groups (lanes p, p+16, p+32, p+48)
#pragma unroll
  for (int off = 16; off <= 32; off <<= 1) {
    aH.x += __shfl_xor(aH.x, off); aH.y += __shfl_xor(aH.y, off);
    aH.z += __shfl_xor(aH.z, off); aH.w += __shfl_xor(aH.w, off);
    aI.x += __shfl_xor(aI.x, off); aI.y += __shfl_xor(aI.y, off);
    aI.z += __shfl_xor(aI.z, off); aI.w += __shfl_xor(aI.w, off);
  }
  if (lane < 16) {
    part[((size_t)(b * 2 + 0) * NPOS + p) * NQ + cy] = make_float4(aH.x, aH.y, aH.z, aH.w);
    part[((size_t)(b * 2 + 1) * NPOS + p) * NQ + cy] = make_float4(aI.x, aI.y, aI.z, aI.w);
  }
}

// ---------------------------------------------------------------------------
// Kernel 3: 4 lanes per (b, region, p): sum NQ partials (contiguous per
// task), 2-stage shfl fold, normalize, validity-zero, write.
// ---------------------------------------------------------------------------
__global__ __launch_bounds__(256) void combine2(
    const float4* __restrict__ part, const unsigned* __restrict__ rsel,
    float* __restrict__ out, int NQ) {
  int gtid = blockIdx.x * blockDim.x + threadIdx.x;
  int g = gtid >> 2, sub = gtid & 3;
  if (g >= BB * 2 * NPOS) return;
  int breg = g / NPOS, p = g - breg * NPOS;
  int b = breg >> 1, reg = breg & 1;

  float4 s = make_float4(0.f, 0.f, 0.f, 0.f);
  for (int c = sub; c < NQ; c += 4) {
    float4 v = part[(size_t)g * NQ + c];
    s.x += v.x; s.y += v.y; s.z += v.z; s.w += v.w;
  }
#pragma unroll
  for (int off = 1; off <= 2; off <<= 1) {
    s.x += __shfl_xor(s.x, off); s.y += __shfl_xor(s.y, off);
    s.z += __shfl_xor(s.z, off); s.w += __shfl_xor(s.w, off);
  }
  if (sub == 0) {
    unsigned rs = rsel[(size_t)b * NPOS + p];
    bool valid = reg ? (((rs >> 4) & 1u) != 0u) : ((rs & 0xFu) != 15u);
    float invL = (valid && s.w > 0.f) ? 1.0f / s.w : 0.0f;
    size_t base = (size_t)reg * BB * 3 * NPOS + (size_t)b * 3 * NPOS + p;
    out[base] = s.x * invL;
    out[base + NPOS] = s.y * invL;
    out[base + 2 * NPOS] = s.z * invL;
  }
}

// ---------------------------------------------------------------------------
extern "C" void kernel_launch(void* const* d_in, const int* in_sizes, int n_in,
                              void* d_out, int out_size, void* d_ws, size_t ws_size,
                              hipStream_t stream) {
  const float* fA = (const float*)d_in[0];
  const float* fT = (const float*)d_in[1];
  const float* It = (const float*)d_in[2];
  const int* mA = (const int*)d_in[3];
  const int* mT = (const int*)d_in[4];
  float* out = (float*)d_out;

  // Workspace layout (float offsets, all multiples of 4 -> 16B aligned)
  const size_t off_Vt = 0;                                 // BB*NPOS float4
  const size_t off_mTb = off_Vt + (size_t)BB * NPOS * 4;   // BB*NPOS uint
  const size_t off_rsel = off_mTb + (size_t)BB * NPOS;     // BB*NPOS uint
  const size_t off_bf = off_rsel + (size_t)BB * NPOS;
  const size_t bfsz = (size_t)BB * NPOS * BCH / 2;         // floats per ushort array
  const size_t off_part = off_bf + 4 * bfsz;

  // NQ must divide 196 (q-tiles); pick largest fitting ws.
  const int cand[5] = {14, 7, 4, 2, 1};
  int NQ = 1;
  for (int i = 0; i < 5; ++i) {
    NQ = cand[i];
    size_t need = (off_part + (size_t)BB * 2 * NPOS * NQ * 4) * sizeof(float);
    if (need <= ws_size) break;
  }
  int ntiles = (NPOS / 16) / NQ;

  float* w = (float*)d_ws;
  float4* Vt = (float4*)(w + off_Vt);
  unsigned* mTb = (unsigned*)(w + off_mTb);
  unsigned* rsel = (unsigned*)(w + off_rsel);
  ushort* Qhi = (ushort*)(w + off_bf);
  ushort* Qlo = (ushort*)(w + off_bf + bfsz);
  ushort* Khi = (ushort*)(w + off_bf + 2 * bfsz);
  ushort* Klo = (ushort*)(w + off_bf + 3 * bfsz);
  float4* part = (float4*)(w + off_part);

  // prep: wave per 4 positions -> BB*NPOS/4 waves = 392 blocks
  prep2<<<(BB * (NPOS / 4) * 64) / 256, 256, 0, stream>>>(
      fA, fT, It, mA, mT, Qhi, Qlo, Khi, Klo, Vt, mTb, rsel);

  dim3 g2(NPOS / 64, NQ, BB);
  attend_mfma<<<g2, 256, 0, stream>>>(Qhi, Qlo, Khi, Klo, Vt, mTb, rsel, part,
                                      NQ, ntiles);

  // combine: 4 lanes per (b,reg,p) task
  int nthr = BB * 2 * NPOS * 4;
  combine2<<<(nthr + 255) / 256, 256, 0, stream>>>(part, rsel, out, NQ);
}